// Round 4
// baseline (459.924 us; speedup 1.0000x reference)
//
#include <hip/hip_runtime.h>
#include <hip/hip_bf16.h>
#include <stdint.h>

typedef __bf16 bf16_t;
typedef __bf16 bf16x4 __attribute__((ext_vector_type(4)));
typedef __bf16 bf16x8 __attribute__((ext_vector_type(8)));
typedef float f32x4 __attribute__((ext_vector_type(4)));

__device__ __forceinline__ float fast_exp2(float x) {
#if __has_builtin(__builtin_amdgcn_exp2f)
  return __builtin_amdgcn_exp2f(x);
#else
  return exp2f(x);
#endif
}

// ---------------- fused f32 -> bf16 convert, all 5 tensors in one dispatch ------------
__global__ void cvt_all(const float* __restrict__ x,  const float* __restrict__ Wq,
                        const float* __restrict__ Wk, const float* __restrict__ Wv,
                        const float* __restrict__ Wo, bf16_t* __restrict__ xb,
                        bf16_t* __restrict__ wqkv, bf16_t* __restrict__ wob) {
  const int bid = blockIdx.x, tid = threadIdx.x;
  const float* src; bf16_t* dst; int i;
  if (bid < 16384)      { src = x;  dst = xb;             i = bid * 256 + tid; }
  else if (bid < 20480) { src = Wq; dst = wqkv;           i = (bid - 16384) * 256 + tid; }
  else if (bid < 21504) { src = Wk; dst = wqkv + 4194304; i = (bid - 20480) * 256 + tid; }
  else if (bid < 22528) { src = Wv; dst = wqkv + 5242880; i = (bid - 21504) * 256 + tid; }
  else                  { src = Wo; dst = wob;            i = (bid - 22528) * 256 + tid; }
  float4 v = ((const float4*)src)[i];
  bf16x4 o = { (bf16_t)v.x, (bf16_t)v.y, (bf16_t)v.z, (bf16_t)v.w };
  *(bf16x4*)(dst + (size_t)i * 4) = o;
}

// ---------------- async global->LDS, 16B per lane ----------------
__device__ __forceinline__ void async_load16(const bf16_t* g, bf16_t* l) {
#if __has_builtin(__builtin_amdgcn_global_load_lds)
  __builtin_amdgcn_global_load_lds((const __attribute__((address_space(1))) void*)g,
                                   (__attribute__((address_space(3))) void*)l, 16, 0, 0);
#else
  *(bf16x8*)l = *(const bf16x8*)g;
#endif
}

// ============ 256x128 8-wave 4-phase pipelined GEMM (balanced-grid variant) ============
// C[M,N] = A[M,K] @ B[N,K]^T.  BM=256, BN=128, BK=64, 512 thr = 8 waves (4M x 2N).
// QKV shape (8192x3072) -> grid 32x24 = 768 = exactly 3 blocks/CU (the 256^2 variant's
// 384 blocks = 1.5/CU measured 138 us, tail-bound). LDS 96 KB -> 1 resident block
// (m201 regime). Per-wave C: 64x64; frag interleave Mrow = mh*128 + mfi*64 + wr*16,
// Ncol = nh*64 + nfi*32 + wc*16 -> every wave reads the SAME A/B half per phase.
// 4 phases/K-tile, quadrant (mh,nh) each: (0,0),(0,1),(1,1),(1,0); A-frags/B-frags
// reused across adjacent phases. Staging: ph1 A0'(2 loads), ph2 B0'(1), ph3 B1'(1),
// ph4 A1'(2) = 6/K-tile. Counted-vmcnt ledger (oldest-first, per wave):
//   end ph1 {B1,A1x2,A0'x2}=5 -> vmcnt(4) lands B1 (ph2)
//   end ph2 {A1x2,A0'x2,B0'}=5 -> vmcnt(3) lands A1 (ph3)
//   end ph3: none (ph4 re-reads resident B0)
//   end ph4 {A0'x2,B0',B1',A1'x2}=6 -> vmcnt(3) lands A0',B0' (next ph1)
// Last tile peel: vmcnt(2) / vmcnt(0) / - / -.  Prologue: 6 loads, vmcnt(3).
template<bool F32OUT, bool VSPLIT>
__global__ __launch_bounds__(512, 2) void gemm_bal(const bf16_t* __restrict__ A,
                                                   const bf16_t* __restrict__ B,
                                                   void* __restrict__ C,
                                                   bf16_t* __restrict__ Vt,
                                                   int NBN, int K, int ldc) {
  __shared__ bf16_t As[2][256 * 64];   // 64 KB
  __shared__ bf16_t Bs[2][128 * 64];   // 32 KB
  const int tid = threadIdx.x;
  const int wave = tid >> 6, lane = tid & 63;
  const int lrow = lane & 15, quad = lane >> 4;
  const int wr = wave >> 1, wc = wave & 1;  // 4M x 2N
  // bijective XCD swizzle (grid % 8 == 0)
  const int nwg = gridDim.x;
  const int wg  = (blockIdx.x & 7) * (nwg >> 3) + (blockIdx.x >> 3);
  const int bm = wg / NBN, bn = wg % NBN;
  const bf16_t* Ag = A + (size_t)bm * 256 * K;
  const bf16_t* Bg = B + (size_t)bn * 128 * K;
  const int srow = tid >> 3;                  // 0..63
  const int schunk = (tid & 7) ^ (srow & 7);  // pre-swizzled global chunk

  f32x4 acc[2][2][2][2] = {};  // [mh][nh][mfi][nfi]
  bf16x8 af[2][2], bfr[2][2];  // [mfi][ks], [nfi][ks]
  const int NT = K >> 6;

  auto stageA = [&](int mh, int bsel, int kk) {
#pragma unroll
    for (int i = 0; i < 2; ++i)
      async_load16(Ag + (size_t)(mh * 128 + i * 64 + srow) * K + kk + schunk * 8,
                   &As[bsel][mh * 8192 + i * 4096 + tid * 8]);
  };
  auto stageB = [&](int nh, int bsel, int kk) {
    async_load16(Bg + (size_t)(nh * 64 + srow) * K + kk + schunk * 8,
                 &Bs[bsel][nh * 4096 + tid * 8]);
  };

#define READ_A(MH)                                                                   \
  _Pragma("unroll")                                                                  \
  for (int mfi = 0; mfi < 2; ++mfi) {                                                \
    const int ra = (MH) * 128 + mfi * 64 + wr * 16 + lrow;                           \
    _Pragma("unroll")                                                                \
    for (int ks = 0; ks < 2; ++ks)                                                   \
      af[mfi][ks] = *(const bf16x8*)&As[buf][ra * 64 +                               \
                        (((ks * 4 + quad) ^ (lrow & 7)) << 3)];                      \
  }
#define READ_B(NH)                                                                   \
  _Pragma("unroll")                                                                  \
  for (int nfi = 0; nfi < 2; ++nfi) {                                                \
    const int rb = (NH) * 64 + nfi * 32 + wc * 16 + lrow;                            \
    _Pragma("unroll")                                                                \
    for (int ks = 0; ks < 2; ++ks)                                                   \
      bfr[nfi][ks] = *(const bf16x8*)&Bs[buf][rb * 64 +                              \
                         (((ks * 4 + quad) ^ (lrow & 7)) << 3)];                     \
  }
#define MFMA_Q(MH, NH)                                                               \
  __builtin_amdgcn_s_setprio(1);                                                     \
  _Pragma("unroll")                                                                  \
  for (int ks = 0; ks < 2; ++ks)                                                     \
    _Pragma("unroll")                                                                \
    for (int mfi = 0; mfi < 2; ++mfi)                                                \
      _Pragma("unroll")                                                              \
      for (int nfi = 0; nfi < 2; ++nfi)                                              \
        acc[MH][NH][mfi][nfi] = __builtin_amdgcn_mfma_f32_16x16x32_bf16(             \
            af[mfi][ks], bfr[nfi][ks], acc[MH][NH][mfi][nfi], 0, 0, 0);              \
  __builtin_amdgcn_s_setprio(0);

  // prologue: tile 0 in steady-state issue order A0(2),B0(1),B1(1),A1(2)
  stageA(0, 0, 0);
  stageB(0, 0, 0);
  stageB(1, 0, 0);
  stageA(1, 0, 0);
  asm volatile("s_waitcnt vmcnt(3)" ::: "memory");  // A0,B0 landed
  __builtin_amdgcn_s_barrier();

  for (int t = 0; t < NT; ++t) {
    const int buf = t & 1, obuf = buf ^ 1;
    const int kn = (t + 1) << 6;
    const bool pf = (t + 1 < NT);
    // ---- phase 1: quadrant (0,0) ----
    READ_A(0)
    READ_B(0)
    if (pf) stageA(0, obuf, kn);
    __builtin_amdgcn_s_barrier();
    asm volatile("s_waitcnt lgkmcnt(0)" ::: "memory");
    MFMA_Q(0, 0)
    if (pf) asm volatile("s_waitcnt vmcnt(4)" ::: "memory");
    else    asm volatile("s_waitcnt vmcnt(2)" ::: "memory");
    __builtin_amdgcn_s_barrier();
    // ---- phase 2: quadrant (0,1) ---- (A0 frags reused)
    READ_B(1)
    if (pf) stageB(0, obuf, kn);
    __builtin_amdgcn_s_barrier();
    asm volatile("s_waitcnt lgkmcnt(0)" ::: "memory");
    MFMA_Q(0, 1)
    if (pf) asm volatile("s_waitcnt vmcnt(3)" ::: "memory");
    else    asm volatile("s_waitcnt vmcnt(0)" ::: "memory");
    __builtin_amdgcn_s_barrier();
    // ---- phase 3: quadrant (1,1) ---- (B1 frags reused)
    READ_A(1)
    if (pf) stageB(1, obuf, kn);
    __builtin_amdgcn_s_barrier();
    asm volatile("s_waitcnt lgkmcnt(0)" ::: "memory");
    MFMA_Q(1, 1)
    __builtin_amdgcn_s_barrier();
    // ---- phase 4: quadrant (1,0) ---- (A1 frags reused; B0 still resident in buf)
    READ_B(0)
    if (pf) stageA(1, obuf, kn);
    __builtin_amdgcn_s_barrier();
    asm volatile("s_waitcnt lgkmcnt(0)" ::: "memory");
    MFMA_Q(1, 0)
    if (pf) asm volatile("s_waitcnt vmcnt(3)" ::: "memory");
    __builtin_amdgcn_s_barrier();
  }
#undef READ_A
#undef READ_B
#undef MFMA_Q

  // ---- epilogue ----
  if (VSPLIT && bn >= 20) {
    // V columns (col >= 2560): store transposed into Vt[(b*4+kvh)*128+d][t]
#pragma unroll
    for (int mh = 0; mh < 2; ++mh)
#pragma unroll
      for (int nh = 0; nh < 2; ++nh)
#pragma unroll
        for (int mfi = 0; mfi < 2; ++mfi)
#pragma unroll
          for (int nfi = 0; nfi < 2; ++nfi) {
            int row = bm * 256 + mh * 128 + mfi * 64 + wr * 16 + quad * 4;  // t (4 consec)
            int cv  = bn * 128 + nh * 64 + nfi * 32 + wc * 16 + lrow - 2560;
            int b = row >> 11, tl = row & 2047;
            bf16x4 o;
#pragma unroll
            for (int r = 0; r < 4; ++r) o[r] = (bf16_t)acc[mh][nh][mfi][nfi][r];
            *(bf16x4*)&Vt[((size_t)(b * 512 + cv)) * 2048 + tl] = o;
          }
    return;
  }
#pragma unroll
  for (int mh = 0; mh < 2; ++mh)
#pragma unroll
    for (int nh = 0; nh < 2; ++nh)
#pragma unroll
      for (int mfi = 0; mfi < 2; ++mfi)
#pragma unroll
        for (int nfi = 0; nfi < 2; ++nfi)
#pragma unroll
          for (int r = 0; r < 4; ++r) {
            int row = bm * 256 + mh * 128 + mfi * 64 + wr * 16 + quad * 4 + r;
            int col = bn * 128 + nh * 64 + nfi * 32 + wc * 16 + lrow;
            if (F32OUT) ((float*)C)[(size_t)row * ldc + col] = acc[mh][nh][mfi][nfi][r];
            else        ((bf16_t*)C)[(size_t)row * ldc + col] = (bf16_t)acc[mh][nh][mfi][nfi][r];
          }
}

// ================= 256x256 8-wave 4-phase pipelined GEMM (T2+T3+T4+T5) =================
// Used where the grid divides the machine exactly (out-proj: 256 blocks = 1/CU).
template<bool F32OUT, bool VSPLIT>
__global__ __launch_bounds__(512, 2) void gemm256(const bf16_t* __restrict__ A,
                                                  const bf16_t* __restrict__ B,
                                                  void* __restrict__ C,
                                                  bf16_t* __restrict__ Vt,
                                                  int NBN, int K, int ldc) {
  __shared__ bf16_t As[2][256 * 64];
  __shared__ bf16_t Bs[2][256 * 64];
  const int tid = threadIdx.x;
  const int wave = tid >> 6, lane = tid & 63;
  const int lrow = lane & 15, quad = lane >> 4;
  const int wr = wave >> 2, wc = wave & 3;
  const int nwg = gridDim.x;
  const int wg  = (blockIdx.x & 7) * (nwg >> 3) + (blockIdx.x >> 3);
  const int bm = wg / NBN, bn = wg % NBN;
  const bf16_t* Ag = A + (size_t)bm * 256 * K;
  const bf16_t* Bg = B + (size_t)bn * 256 * K;
  const int srow = tid >> 3;
  const int schunk = (tid & 7) ^ (srow & 7);

  f32x4 acc[2][2][4][2] = {};  // [mh][nh][mfi][nfi]
  bf16x8 af[4][2], bfr[2][2];
  const int NT = K >> 6;

  auto stageA = [&](int mh, int bsel, int kk) {
#pragma unroll
    for (int i = 0; i < 2; ++i)
      async_load16(Ag + (size_t)(mh * 128 + i * 64 + srow) * K + kk + schunk * 8,
                   &As[bsel][mh * 8192 + i * 4096 + tid * 8]);
  };
  auto stageB = [&](int nh, int bsel, int kk) {
#pragma unroll
    for (int i = 0; i < 2; ++i)
      async_load16(Bg + (size_t)(nh * 128 + i * 64 + srow) * K + kk + schunk * 8,
                   &Bs[bsel][nh * 8192 + i * 4096 + tid * 8]);
  };

#define READ_A(MH)                                                                   \
  _Pragma("unroll")                                                                  \
  for (int mfi = 0; mfi < 4; ++mfi) {                                                \
    const int ra = (MH) * 128 + mfi * 32 + wr * 16 + lrow;                           \
    _Pragma("unroll")                                                                \
    for (int ks = 0; ks < 2; ++ks)                                                   \
      af[mfi][ks] = *(const bf16x8*)&As[buf][ra * 64 +                               \
                        (((ks * 4 + quad) ^ (lrow & 7)) << 3)];                      \
  }
#define READ_B(NH)                                                                   \
  _Pragma("unroll")                                                                  \
  for (int nfi = 0; nfi < 2; ++nfi) {                                                \
    const int rb = (NH) * 128 + nfi * 64 + wc * 16 + lrow;                           \
    _Pragma("unroll")                                                                \
    for (int ks = 0; ks < 2; ++ks)                                                   \
      bfr[nfi][ks] = *(const bf16x8*)&Bs[buf][rb * 64 +                              \
                         (((ks * 4 + quad) ^ (lrow & 7)) << 3)];                     \
  }
#define MFMA_Q(MH, NH)                                                               \
  __builtin_amdgcn_s_setprio(1);                                                     \
  _Pragma("unroll")                                                                  \
  for (int ks = 0; ks < 2; ++ks)                                                     \
    _Pragma("unroll")                                                                \
    for (int mfi = 0; mfi < 4; ++mfi)                                                \
      _Pragma("unroll")                                                              \
      for (int nfi = 0; nfi < 2; ++nfi)                                              \
        acc[MH][NH][mfi][nfi] = __builtin_amdgcn_mfma_f32_16x16x32_bf16(             \
            af[mfi][ks], bfr[nfi][ks], acc[MH][NH][mfi][nfi], 0, 0, 0);              \
  __builtin_amdgcn_s_setprio(0);

  stageA(0, 0, 0);
  stageB(0, 0, 0);
  stageB(1, 0, 0);
  stageA(1, 0, 0);
  asm volatile("s_waitcnt vmcnt(4)" ::: "memory");
  __builtin_amdgcn_s_barrier();

  for (int t = 0; t < NT; ++t) {
    const int buf = t & 1, obuf = buf ^ 1;
    const int kn = (t + 1) << 6;
    const bool pf = (t + 1 < NT);
    READ_A(0)
    READ_B(0)
    if (pf) stageA(0, obuf, kn);
    __builtin_amdgcn_s_barrier();
    asm volatile("s_waitcnt lgkmcnt(0)" ::: "memory");
    MFMA_Q(0, 0)
    if (pf) asm volatile("s_waitcnt vmcnt(4)" ::: "memory");
    else    asm volatile("s_waitcnt vmcnt(2)" ::: "memory");
    __builtin_amdgcn_s_barrier();
    READ_B(1)
    if (pf) stageB(0, obuf, kn);
    __builtin_amdgcn_s_barrier();
    asm volatile("s_waitcnt lgkmcnt(0)" ::: "memory");
    MFMA_Q(0, 1)
    if (pf) asm volatile("s_waitcnt vmcnt(4)" ::: "memory");
    else    asm volatile("s_waitcnt vmcnt(0)" ::: "memory");
    __builtin_amdgcn_s_barrier();
    READ_A(1)
    if (pf) stageB(1, obuf, kn);
    __builtin_amdgcn_s_barrier();
    asm volatile("s_waitcnt lgkmcnt(0)" ::: "memory");
    MFMA_Q(1, 1)
    __builtin_amdgcn_s_barrier();
    READ_B(0)
    if (pf) stageA(1, obuf, kn);
    __builtin_amdgcn_s_barrier();
    asm volatile("s_waitcnt lgkmcnt(0)" ::: "memory");
    MFMA_Q(1, 0)
    if (pf) asm volatile("s_waitcnt vmcnt(4)" ::: "memory");
    __builtin_amdgcn_s_barrier();
  }
#undef READ_A
#undef READ_B
#undef MFMA_Q

  if (VSPLIT && bn >= 10) {
#pragma unroll
    for (int mh = 0; mh < 2; ++mh)
#pragma unroll
      for (int nh = 0; nh < 2; ++nh)
#pragma unroll
        for (int mfi = 0; mfi < 4; ++mfi)
#pragma unroll
          for (int nfi = 0; nfi < 2; ++nfi) {
            int row = bm * 256 + mh * 128 + mfi * 32 + wr * 16 + quad * 4;
            int cv  = bn * 256 + nh * 128 + nfi * 64 + wc * 16 + lrow - 2560;
            int b = row >> 11, tl = row & 2047;
            bf16x4 o;
#pragma unroll
            for (int r = 0; r < 4; ++r) o[r] = (bf16_t)acc[mh][nh][mfi][nfi][r];
            *(bf16x4*)&Vt[((size_t)(b * 512 + cv)) * 2048 + tl] = o;
          }
    return;
  }
#pragma unroll
  for (int mh = 0; mh < 2; ++mh)
#pragma unroll
    for (int nh = 0; nh < 2; ++nh)
#pragma unroll
      for (int mfi = 0; mfi < 4; ++mfi)
#pragma unroll
        for (int nfi = 0; nfi < 2; ++nfi)
#pragma unroll
          for (int r = 0; r < 4; ++r) {
            int row = bm * 256 + mh * 128 + mfi * 32 + wr * 16 + quad * 4 + r;
            int col = bn * 256 + nh * 128 + nfi * 64 + wc * 16 + lrow;
            if (F32OUT) ((float*)C)[(size_t)row * ldc + col] = acc[mh][nh][mfi][nfi][r];
            else        ((bf16_t*)C)[(size_t)row * ldc + col] = (bf16_t)acc[mh][nh][mfi][nfi][r];
          }
}

// ---------------- RoPE (in-place, layout (rows, nheads, 128), row stride param) ----------
__global__ void rope_kernel(bf16_t* __restrict__ X, const float* __restrict__ F,
                            int hshift, int stride) {
  int i = blockIdx.x * blockDim.x + threadIdx.x;
  int d = i & 63;
  int h = (i >> 6) & ((1 << hshift) - 1);
  int row = i >> (6 + hshift);
  int t = row & 2047;
  float c = F[t * 128 + d * 2];
  float s = F[t * 128 + d * 2 + 1];
  size_t base = (size_t)row * stride + h * 128 + d;
  float q0 = (float)X[base];
  float q1 = (float)X[base + 64];
  X[base]      = (bf16_t)(q0 * c - q1 * s);
  X[base + 64] = (bf16_t)(q1 * c + q0 * s);
}

// ---------------- Flash attention, causal, GQA 16q/4kv, D=128 ----------------
// K/V double-buffered in LDS; ONE __syncthreads per K-tile; T13 defer-max (thr=8, log2).
__global__ __launch_bounds__(256, 2) void attn_kernel(const bf16_t* __restrict__ QKV,
                                                      const float* __restrict__ F,
                                                      const bf16_t* __restrict__ Vt,
                                                      bf16_t* __restrict__ O) {
  __shared__ bf16_t Ks[2][64 * 128];   // [buf][key][d], chunk-swizzled
  __shared__ bf16_t Vs[2][128 * 64];   // [buf][d][key], chunk-swizzled
  __shared__ bf16_t Ps[4 * 32 * 64];   // per-wave, chunk-swizzled
  const int tid = threadIdx.x;
  const int wave = tid >> 6, lane = tid & 63;
  const int lrow = lane & 15, quad = lane >> 4;
  const int bh = blockIdx.y, b = bh >> 4, h = bh & 15, kvh = h >> 2;
  const size_t qoff  = ((size_t)b * 2048) * 2560 + (size_t)h * 128;
  const size_t koff  = ((size_t)b * 2048) * 2560 + 2048 + (size_t)kvh * 128;
  const size_t vtoff = ((size_t)(b * 4 + kvh) * 128) * 2048;
  const float qsc = 0.08838834764831845f * 1.44269504088896340736f;  // 1/sqrt(128)*log2(e)
  bf16_t* Pw = Ps + wave * (32 * 64);
  const float2* F2 = (const float2*)F;  // [t][64] (cos,sin)

  const int krow_l = tid >> 4;                   // 0..15
  const int kdc    = (tid & 15) ^ (krow_l & 7);  // K chunk swizzle
  const int vrow_l = tid >> 3;                   // 0..31
  const int vkc    = (tid & 7) ^ (vrow_l & 7);   // V chunk swizzle

  auto stage = [&](int kt, int bsel) {
    const bf16_t* Kg = QKV + koff + (size_t)(kt * 64) * 2560;
    const bf16_t* Vg = Vt + vtoff + kt * 64;
    bf16_t* Kd = &Ks[bsel][0];
    bf16_t* Vd = &Vs[bsel][0];
#pragma unroll
    for (int c4 = 0; c4 < 4; ++c4) {
      int ci = c4 * 256 + tid;
      async_load16(Kg + (size_t)(c4 * 16 + krow_l) * 2560 + kdc * 8, Kd + ci * 8);
      async_load16(Vg + (size_t)(c4 * 32 + vrow_l) * 2048 + vkc * 8, Vd + ci * 8);
    }
  };

  for (int phase = 0; phase < 2; ++phase) {
    const int qt = phase ? (15 - blockIdx.x) : blockIdx.x;
    const int qbase = qt * 128 + wave * 32;

    // Q B-frags with fused RoPE + scale: B[n=q][k=d]
    bf16x8 qf[2][4];
#pragma unroll
    for (int nt2 = 0; nt2 < 2; ++nt2) {
      const int t = qbase + nt2 * 16 + lrow;  // 0..2047
      const bf16_t* qp = QKV + qoff + (size_t)t * 2560 + quad * 8;
      bf16x8 raw[4];
#pragma unroll
      for (int ks = 0; ks < 4; ++ks) raw[ks] = *(const bf16x8*)(qp + ks * 32);
#pragma unroll
      for (int ks2 = 0; ks2 < 2; ++ks2) {
        bf16x8 lo, hi;
#pragma unroll
        for (int j = 0; j < 8; ++j) {
          int d = ks2 * 32 + quad * 8 + j;  // < 64
          float2 cs = F2[t * 64 + d];
          float q0 = (float)raw[ks2][j], q1 = (float)raw[ks2 + 2][j];
          lo[j] = (bf16_t)((q0 * cs.x - q1 * cs.y) * qsc);
          hi[j] = (bf16_t)((q1 * cs.x + q0 * cs.y) * qsc);
        }
        qf[nt2][ks2]     = lo;
        qf[nt2][ks2 + 2] = hi;
      }
    }

    f32x4 Oacc[2][8] = {};
    float m_r[2] = {-1.0e30f, -1.0e30f};
    float l_r[2] = {0.f, 0.f};
    const int kt_end = 2 * qt + 2;

    stage(0, 0);  // prime the pipeline

    for (int kt = 0; kt < kt_end; ++kt) {
      __syncthreads();
      if (kt + 1 < kt_end) stage(kt + 1, (kt + 1) & 1);
      const bf16_t* Kb_ = &Ks[kt & 1][0];
      const bf16_t* Vb_ = &Vs[kt & 1][0];

      if (kt * 64 <= qbase + 31) {  // wave-uniform skip of fully-masked tiles
        // S^T = K Q^T : C[m=key][n=q]
        f32x4 S[2][4] = {};
#pragma unroll
        for (int ks = 0; ks < 4; ++ks) {
          bf16x8 kf[4];
#pragma unroll
          for (int mt = 0; mt < 4; ++mt) {
            int dc = (ks * 4 + quad) ^ (lrow & 7);
            kf[mt] = *(const bf16x8*)&Kb_[(mt * 16 + lrow) * 128 + dc * 8];
          }
#pragma unroll
          for (int nt2 = 0; nt2 < 2; ++nt2)
#pragma unroll
            for (int mt = 0; mt < 4; ++mt)
              S[nt2][mt] = __builtin_amdgcn_mfma_f32_16x16x32_bf16(kf[mt], qf[nt2][ks], S[nt2][mt], 0, 0, 0);
        }
        // causal mask (diagonal tiles only). S^T: key=row, q=col.
        if (kt * 64 + 63 > qbase) {
#pragma unroll
          for (int nt2 = 0; nt2 < 2; ++nt2) {
            int q = qbase + nt2 * 16 + lrow;
#pragma unroll
            for (int mt = 0; mt < 4; ++mt) {
              int key0 = kt * 64 + mt * 16 + quad * 4;
#pragma unroll
              for (int r = 0; r < 4; ++r)
                if (key0 + r > q) S[nt2][mt][r] = -1.0e30f;
            }
          }
        }
        // online softmax (log2 domain); P -> Pw with chunk swizzle
        float alpha[2];
#pragma unroll
        for (int nt2 = 0; nt2 < 2; ++nt2) {
          float mx = -1.0e30f;
#pragma unroll
          for (int mt = 0; mt < 4; ++mt)
#pragma unroll
            for (int r = 0; r < 4; ++r) mx = fmaxf(mx, S[nt2][mt][r]);
          mx = fmaxf(mx, __shfl_xor(mx, 16, 64));
          mx = fmaxf(mx, __shfl_xor(mx, 32, 64));
          // T13 defer-max: only ratchet m when the tile max exceeds it by > 8
          float mold = m_r[nt2];
          float mnew = (mx - mold <= 8.0f) ? mold : mx;
          alpha[nt2] = fast_exp2(mold - mnew);  // exactly 1.0 when deferred
          m_r[nt2] = mnew;
          float rs = 0.f;
          const int prow = nt2 * 16 + lrow;
          const int pbase = prow * 64 + ((quad & 1) << 2);
#pragma unroll
          for (int mt = 0; mt < 4; ++mt) {
            bf16x4 pk;
#pragma unroll
            for (int r = 0; r < 4; ++r) {
              float p = fast_exp2(S[nt2][mt][r] - mnew);
              rs += p;
              pk[r] = (bf16_t)p;
            }
            int c8 = ((mt * 2 + (quad >> 1)) ^ (prow & 7)) << 3;
            *(bf16x4*)&Pw[pbase + c8] = pk;
          }
          rs += __shfl_xor(rs, 16, 64);
          rs += __shfl_xor(rs, 32, 64);
          l_r[nt2] = l_r[nt2] * alpha[nt2] + rs;
        }
        // lazy O rescale (rare after T13)
        bool nz = (alpha[0] != 1.f) || (alpha[1] != 1.f);
        if (__ballot(nz) != 0ull) {
#pragma unroll
          for (int mt2 = 0; mt2 < 2; ++mt2)
#pragma unroll
            for (int r = 0; r < 4; ++r) {
              float av = __shfl(alpha[mt2], quad * 4 + r, 16);
#pragma unroll
              for (int dt = 0; dt < 8; ++dt) Oacc[mt2][dt][r] *= av;
            }
        }
        // O += P V : A=P from Pw (swizzled), B=V^T from Vs (swizzled)
#pragma unroll
        for (int ks2 = 0; ks2 < 2; ++ks2) {
          bf16x8 ap[2];
#pragma unroll
          for (int mt2 = 0; mt2 < 2; ++mt2) {
            int prow = mt2 * 16 + lrow;
            ap[mt2] = *(const bf16x8*)&Pw[prow * 64 + (((ks2 * 4 + quad) ^ (prow & 7)) << 3)];
          }
          int dc = (ks2 * 4 + quad) ^ (lrow & 7);
#pragma unroll
          for (int dt = 0; dt < 8; ++dt) {
            bf16x8 bv = *(const bf16x8*)&Vb_[(dt * 16 + lrow) * 64 + dc * 8];
#pragma unroll
            for (int mt2 = 0; mt2 < 2; ++mt2)
              Oacc[mt2][dt] = __builtin_amdgcn_mfma_f32_16x16x32_bf16(ap[mt2], bv, Oacc[mt2][dt], 0, 0, 0);
          }
        }
      }
    }

    // epilogue: O /= l, store bf16 (Ab stride 2048)
#pragma unroll
    for (int mt2 = 0; mt2 < 2; ++mt2)
#pragma unroll
      for (int r = 0; r < 4; ++r) {
        float lv = __shfl(l_r[mt2], quad * 4 + r, 16);
        float inv = 1.0f / lv;
        int row = qbase + mt2 * 16 + quad * 4 + r;
#pragma unroll
        for (int dt = 0; dt < 8; ++dt)
          O[(size_t)b * 2048 * 2048 + (size_t)row * 2048 + h * 128 + dt * 16 + lrow] =
              (bf16_t)(Oacc[mt2][dt][r] * inv);
      }
  }
}

// ---------------- launch ----------------
extern "C" void kernel_launch(void* const* d_in, const int* in_sizes, int n_in,
                              void* d_out, int out_size, void* d_ws, size_t ws_size,
                              hipStream_t stream) {
  const float* x  = (const float*)d_in[0];
  const float* fc = (const float*)d_in[1];
  const float* Wq = (const float*)d_in[2];
  const float* Wk = (const float*)d_in[3];
  const float* Wv = (const float*)d_in[4];
  const float* Wo = (const float*)d_in[5];
  float* out = (float*)d_out;

  char* ws = (char*)d_ws;
  size_t off = 0;
  auto alloc = [&](size_t bytes) { char* p = ws + off; off += bytes; return p; };
  bf16_t* xb    = (bf16_t*)alloc((size_t)8192 * 2048 * 2);  // x bf16
  bf16_t* Wqkvb = (bf16_t*)alloc((size_t)3072 * 2048 * 2);  // [Wq; Wk; Wv] rows
  bf16_t* Wob   = (bf16_t*)alloc((size_t)2048 * 2048 * 2);
  bf16_t* QKVb  = (bf16_t*)alloc((size_t)8192 * 2560 * 2);  // [t][ Q(2048) | K(512) ]
  bf16_t* Ab    = (bf16_t*)alloc((size_t)8192 * 2048 * 2);
  bf16_t* Vtb   = (bf16_t*)alloc((size_t)2048 * 2048 * 2);  // V^T [(b*4+kvh)*128+d][t]
  (void)ws_size; (void)in_sizes; (void)n_in; (void)out_size;

  cvt_all<<<26624, 256, 0, stream>>>(x, Wq, Wk, Wv, Wo, xb, Wqkvb, Wob);

  // fused QKV projection: 256x128 tiles -> grid 32x24 = 768 = exactly 3/CU (balanced)
  gemm_bal<false, true><<<768, 512, 0, stream>>>(xb, Wqkvb, QKVb, Vtb, 24, 2048, 2560);

  // RoPE on K only (Q rope fused into attention); K cols 2048..2559, stride 2560
  rope_kernel<<<8192, 256, 0, stream>>>(QKVb + 2048, fc, 2, 2560);

  attn_kernel<<<dim3(8, 64), 256, 0, stream>>>(QKVb, fc, Vtb, Ab);

  // output projection (256^2 4-phase, 256 blocks = exactly 1/CU), f32 out
  gemm256<true, false><<<256, 512, 0, stream>>>(Ab, Wob, out, nullptr, 8, 2048, 2048);
}

// Round 5
// 429.687 us; speedup vs baseline: 1.0704x; 1.0704x over previous
//
#include <hip/hip_runtime.h>
#include <hip/hip_bf16.h>
#include <stdint.h>

typedef __bf16 bf16_t;
typedef __bf16 bf16x4 __attribute__((ext_vector_type(4)));
typedef __bf16 bf16x8 __attribute__((ext_vector_type(8)));
typedef float f32x4 __attribute__((ext_vector_type(4)));

__device__ __forceinline__ float fast_exp2(float x) {
#if __has_builtin(__builtin_amdgcn_exp2f)
  return __builtin_amdgcn_exp2f(x);
#else
  return exp2f(x);
#endif
}

// ---------------- fused f32 -> bf16 convert, all 5 tensors in one dispatch ------------
__global__ void cvt_all(const float* __restrict__ x,  const float* __restrict__ Wq,
                        const float* __restrict__ Wk, const float* __restrict__ Wv,
                        const float* __restrict__ Wo, bf16_t* __restrict__ xb,
                        bf16_t* __restrict__ wqkv, bf16_t* __restrict__ wob) {
  const int bid = blockIdx.x, tid = threadIdx.x;
  const float* src; bf16_t* dst; int i;
  if (bid < 16384)      { src = x;  dst = xb;             i = bid * 256 + tid; }
  else if (bid < 20480) { src = Wq; dst = wqkv;           i = (bid - 16384) * 256 + tid; }
  else if (bid < 21504) { src = Wk; dst = wqkv + 4194304; i = (bid - 20480) * 256 + tid; }
  else if (bid < 22528) { src = Wv; dst = wqkv + 5242880; i = (bid - 21504) * 256 + tid; }
  else                  { src = Wo; dst = wob;            i = (bid - 22528) * 256 + tid; }
  float4 v = ((const float4*)src)[i];
  bf16x4 o = { (bf16_t)v.x, (bf16_t)v.y, (bf16_t)v.z, (bf16_t)v.w };
  *(bf16x4*)(dst + (size_t)i * 4) = o;
}

// ---------------- async global->LDS, 16B per lane ----------------
__device__ __forceinline__ void async_load16(const bf16_t* g, bf16_t* l) {
#if __has_builtin(__builtin_amdgcn_global_load_lds)
  __builtin_amdgcn_global_load_lds((const __attribute__((address_space(1))) void*)g,
                                   (__attribute__((address_space(3))) void*)l, 16, 0, 0);
#else
  *(bf16x8*)l = *(const bf16x8*)g;
#endif
}

// ========== 256x128 8-wave 2-PHASE pipelined GEMM (balanced grid, 16 MFMA/phase) ========
// C[M,N] = A[M,K] @ B[N,K]^T.  BM=256, BN=128, BK=64, 512 thr = 8 waves (4M x 2N).
// QKV shape -> grid 32x24 = 768 = exactly 3 rounds of 1 block/CU (balanced; the 256^2
// variant's 384 blocks = 1.5/CU was tail-bound at 138 us). LDS 96 KB.
// LESSON (r4): the 4-phase variant's 8-MFMA clusters were too small vs per-phase barrier
// overhead (27.9% MfmaUtil, 151 us). This variant keeps gemm256's 16-MFMA clusters:
//   ph-A: ds-read A0 + B(both halves, frags held in regs) | stage A0'(2)+B0'(1)+B1'(1)
//         | barrier | lgkm0 | 16 MFMA (mh=0 x nh=0,1)
//   ph-B: ds-read A1 | stage A1'(2) | barrier | lgkm0 | 16 MFMA (mh=1 x nh=0,1)
// Counted-vmcnt ledger (6 loads/tile/wave, oldest-first):
//   prologue {A0x2,B0,B1,A1x2}: vmcnt(2) lands A0,B0,B1
//   end ph-A {A1x2, A0'x2,B0',B1'}=6 -> vmcnt(4) lands A1   (last tile: vmcnt(0))
//   end ph-B {A0'x2,B0',B1',A1'x2}=6 -> vmcnt(2) lands A0',B0',B1'  (last tile: none)
// Cross-wave safety: each wave waits for ITS loads, then barrier -> all landed (same
// induction as the passing gemm256).
template<bool F32OUT, bool VSPLIT>
__global__ __launch_bounds__(512, 2) void gemm_bal2(const bf16_t* __restrict__ A,
                                                    const bf16_t* __restrict__ B,
                                                    void* __restrict__ C,
                                                    bf16_t* __restrict__ Vt,
                                                    int NBN, int K, int ldc) {
  __shared__ bf16_t As[2][256 * 64];   // 64 KB
  __shared__ bf16_t Bs[2][128 * 64];   // 32 KB
  const int tid = threadIdx.x;
  const int wave = tid >> 6, lane = tid & 63;
  const int lrow = lane & 15, quad = lane >> 4;
  const int wr = wave >> 1, wc = wave & 1;  // 4M x 2N
  // bijective XCD swizzle (grid % 8 == 0)
  const int nwg = gridDim.x;
  const int wg  = (blockIdx.x & 7) * (nwg >> 3) + (blockIdx.x >> 3);
  const int bm = wg / NBN, bn = wg % NBN;
  const bf16_t* Ag = A + (size_t)bm * 256 * K;
  const bf16_t* Bg = B + (size_t)bn * 128 * K;
  const int srow = tid >> 3;                  // 0..63
  const int schunk = (tid & 7) ^ (srow & 7);  // pre-swizzled global chunk

  f32x4 acc[2][2][2][2] = {};  // [mh][nh][mfi][nfi]
  bf16x8 af[2][2];             // [mfi][ks]        (A half, re-read per phase)
  bf16x8 bfr[2][2][2];         // [nh][nfi][ks]    (full B, lives across both phases)
  const int NT = K >> 6;

  auto stageA = [&](int mh, int bsel, int kk) {
#pragma unroll
    for (int i = 0; i < 2; ++i)
      async_load16(Ag + (size_t)(mh * 128 + i * 64 + srow) * K + kk + schunk * 8,
                   &As[bsel][mh * 8192 + i * 4096 + tid * 8]);
  };
  auto stageB = [&](int nh, int bsel, int kk) {
    async_load16(Bg + (size_t)(nh * 64 + srow) * K + kk + schunk * 8,
                 &Bs[bsel][nh * 4096 + tid * 8]);
  };

#define READ_A(MH)                                                                   \
  _Pragma("unroll")                                                                  \
  for (int mfi = 0; mfi < 2; ++mfi) {                                                \
    const int ra = (MH) * 128 + mfi * 64 + wr * 16 + lrow;                           \
    _Pragma("unroll")                                                                \
    for (int ks = 0; ks < 2; ++ks)                                                   \
      af[mfi][ks] = *(const bf16x8*)&As[buf][ra * 64 +                               \
                        (((ks * 4 + quad) ^ (lrow & 7)) << 3)];                      \
  }
#define READ_B_ALL                                                                   \
  _Pragma("unroll")                                                                  \
  for (int nh = 0; nh < 2; ++nh)                                                     \
    _Pragma("unroll")                                                                \
    for (int nfi = 0; nfi < 2; ++nfi) {                                              \
      const int rb = nh * 64 + nfi * 32 + wc * 16 + lrow;                            \
      _Pragma("unroll")                                                              \
      for (int ks = 0; ks < 2; ++ks)                                                 \
        bfr[nh][nfi][ks] = *(const bf16x8*)&Bs[buf][rb * 64 +                        \
                               (((ks * 4 + quad) ^ (lrow & 7)) << 3)];               \
    }
#define MFMA_ROW(MH)                                                                 \
  __builtin_amdgcn_s_setprio(1);                                                     \
  _Pragma("unroll")                                                                  \
  for (int ks = 0; ks < 2; ++ks)                                                     \
    _Pragma("unroll")                                                                \
    for (int nh = 0; nh < 2; ++nh)                                                   \
      _Pragma("unroll")                                                              \
      for (int mfi = 0; mfi < 2; ++mfi)                                              \
        _Pragma("unroll")                                                            \
        for (int nfi = 0; nfi < 2; ++nfi)                                            \
          acc[MH][nh][mfi][nfi] = __builtin_amdgcn_mfma_f32_16x16x32_bf16(           \
              af[mfi][ks], bfr[nh][nfi][ks], acc[MH][nh][mfi][nfi], 0, 0, 0);        \
  __builtin_amdgcn_s_setprio(0);

  // prologue: tile 0 in steady-state issue order A0(2),B0(1),B1(1),A1(2)
  stageA(0, 0, 0);
  stageB(0, 0, 0);
  stageB(1, 0, 0);
  stageA(1, 0, 0);
  asm volatile("s_waitcnt vmcnt(2)" ::: "memory");  // A0,B0,B1 landed
  __builtin_amdgcn_s_barrier();

  for (int t = 0; t < NT; ++t) {
    const int buf = t & 1, obuf = buf ^ 1;
    const int kn = (t + 1) << 6;
    const bool pf = (t + 1 < NT);
    // ---- phase A: mh=0 row (quadrants (0,0),(0,1)) ----
    READ_A(0)
    READ_B_ALL
    if (pf) { stageA(0, obuf, kn); stageB(0, obuf, kn); stageB(1, obuf, kn); }
    __builtin_amdgcn_s_barrier();
    asm volatile("s_waitcnt lgkmcnt(0)" ::: "memory");
    MFMA_ROW(0)
    if (pf) asm volatile("s_waitcnt vmcnt(4)" ::: "memory");
    else    asm volatile("s_waitcnt vmcnt(0)" ::: "memory");
    __builtin_amdgcn_s_barrier();
    // ---- phase B: mh=1 row (quadrants (1,0),(1,1)); B frags reused from regs ----
    READ_A(1)
    if (pf) stageA(1, obuf, kn);
    __builtin_amdgcn_s_barrier();
    asm volatile("s_waitcnt lgkmcnt(0)" ::: "memory");
    MFMA_ROW(1)
    if (pf) asm volatile("s_waitcnt vmcnt(2)" ::: "memory");
    __builtin_amdgcn_s_barrier();
  }
#undef READ_A
#undef READ_B_ALL
#undef MFMA_ROW

  // ---- epilogue ----
  if (VSPLIT && bn >= 20) {
    // V columns (col >= 2560): store transposed into Vt[(b*4+kvh)*128+d][t]
#pragma unroll
    for (int mh = 0; mh < 2; ++mh)
#pragma unroll
      for (int nh = 0; nh < 2; ++nh)
#pragma unroll
        for (int mfi = 0; mfi < 2; ++mfi)
#pragma unroll
          for (int nfi = 0; nfi < 2; ++nfi) {
            int row = bm * 256 + mh * 128 + mfi * 64 + wr * 16 + quad * 4;  // t (4 consec)
            int cv  = bn * 128 + nh * 64 + nfi * 32 + wc * 16 + lrow - 2560;
            int b = row >> 11, tl = row & 2047;
            bf16x4 o;
#pragma unroll
            for (int r = 0; r < 4; ++r) o[r] = (bf16_t)acc[mh][nh][mfi][nfi][r];
            *(bf16x4*)&Vt[((size_t)(b * 512 + cv)) * 2048 + tl] = o;
          }
    return;
  }
#pragma unroll
  for (int mh = 0; mh < 2; ++mh)
#pragma unroll
    for (int nh = 0; nh < 2; ++nh)
#pragma unroll
      for (int mfi = 0; mfi < 2; ++mfi)
#pragma unroll
        for (int nfi = 0; nfi < 2; ++nfi)
#pragma unroll
          for (int r = 0; r < 4; ++r) {
            int row = bm * 256 + mh * 128 + mfi * 64 + wr * 16 + quad * 4 + r;
            int col = bn * 128 + nh * 64 + nfi * 32 + wc * 16 + lrow;
            if (F32OUT) ((float*)C)[(size_t)row * ldc + col] = acc[mh][nh][mfi][nfi][r];
            else        ((bf16_t*)C)[(size_t)row * ldc + col] = (bf16_t)acc[mh][nh][mfi][nfi][r];
          }
}

// ================= 256x256 8-wave 4-phase pipelined GEMM (T2+T3+T4+T5) =================
// Used where the grid divides the machine exactly (out-proj: 256 blocks = 1/CU).
template<bool F32OUT, bool VSPLIT>
__global__ __launch_bounds__(512, 2) void gemm256(const bf16_t* __restrict__ A,
                                                  const bf16_t* __restrict__ B,
                                                  void* __restrict__ C,
                                                  bf16_t* __restrict__ Vt,
                                                  int NBN, int K, int ldc) {
  __shared__ bf16_t As[2][256 * 64];
  __shared__ bf16_t Bs[2][256 * 64];
  const int tid = threadIdx.x;
  const int wave = tid >> 6, lane = tid & 63;
  const int lrow = lane & 15, quad = lane >> 4;
  const int wr = wave >> 2, wc = wave & 3;
  const int nwg = gridDim.x;
  const int wg  = (blockIdx.x & 7) * (nwg >> 3) + (blockIdx.x >> 3);
  const int bm = wg / NBN, bn = wg % NBN;
  const bf16_t* Ag = A + (size_t)bm * 256 * K;
  const bf16_t* Bg = B + (size_t)bn * 256 * K;
  const int srow = tid >> 3;
  const int schunk = (tid & 7) ^ (srow & 7);

  f32x4 acc[2][2][4][2] = {};  // [mh][nh][mfi][nfi]
  bf16x8 af[4][2], bfr[2][2];
  const int NT = K >> 6;

  auto stageA = [&](int mh, int bsel, int kk) {
#pragma unroll
    for (int i = 0; i < 2; ++i)
      async_load16(Ag + (size_t)(mh * 128 + i * 64 + srow) * K + kk + schunk * 8,
                   &As[bsel][mh * 8192 + i * 4096 + tid * 8]);
  };
  auto stageB = [&](int nh, int bsel, int kk) {
#pragma unroll
    for (int i = 0; i < 2; ++i)
      async_load16(Bg + (size_t)(nh * 128 + i * 64 + srow) * K + kk + schunk * 8,
                   &Bs[bsel][nh * 8192 + i * 4096 + tid * 8]);
  };

#define READ_A(MH)                                                                   \
  _Pragma("unroll")                                                                  \
  for (int mfi = 0; mfi < 4; ++mfi) {                                                \
    const int ra = (MH) * 128 + mfi * 32 + wr * 16 + lrow;                           \
    _Pragma("unroll")                                                                \
    for (int ks = 0; ks < 2; ++ks)                                                   \
      af[mfi][ks] = *(const bf16x8*)&As[buf][ra * 64 +                               \
                        (((ks * 4 + quad) ^ (lrow & 7)) << 3)];                      \
  }
#define READ_B(NH)                                                                   \
  _Pragma("unroll")                                                                  \
  for (int nfi = 0; nfi < 2; ++nfi) {                                                \
    const int rb = (NH) * 128 + nfi * 64 + wc * 16 + lrow;                           \
    _Pragma("unroll")                                                                \
    for (int ks = 0; ks < 2; ++ks)                                                   \
      bfr[nfi][ks] = *(const bf16x8*)&Bs[buf][rb * 64 +                              \
                         (((ks * 4 + quad) ^ (lrow & 7)) << 3)];                     \
  }
#define MFMA_Q(MH, NH)                                                               \
  __builtin_amdgcn_s_setprio(1);                                                     \
  _Pragma("unroll")                                                                  \
  for (int ks = 0; ks < 2; ++ks)                                                     \
    _Pragma("unroll")                                                                \
    for (int mfi = 0; mfi < 4; ++mfi)                                                \
      _Pragma("unroll")                                                              \
      for (int nfi = 0; nfi < 2; ++nfi)                                              \
        acc[MH][NH][mfi][nfi] = __builtin_amdgcn_mfma_f32_16x16x32_bf16(             \
            af[mfi][ks], bfr[nfi][ks], acc[MH][NH][mfi][nfi], 0, 0, 0);              \
  __builtin_amdgcn_s_setprio(0);

  stageA(0, 0, 0);
  stageB(0, 0, 0);
  stageB(1, 0, 0);
  stageA(1, 0, 0);
  asm volatile("s_waitcnt vmcnt(4)" ::: "memory");
  __builtin_amdgcn_s_barrier();

  for (int t = 0; t < NT; ++t) {
    const int buf = t & 1, obuf = buf ^ 1;
    const int kn = (t + 1) << 6;
    const bool pf = (t + 1 < NT);
    READ_A(0)
    READ_B(0)
    if (pf) stageA(0, obuf, kn);
    __builtin_amdgcn_s_barrier();
    asm volatile("s_waitcnt lgkmcnt(0)" ::: "memory");
    MFMA_Q(0, 0)
    if (pf) asm volatile("s_waitcnt vmcnt(4)" ::: "memory");
    else    asm volatile("s_waitcnt vmcnt(2)" ::: "memory");
    __builtin_amdgcn_s_barrier();
    READ_B(1)
    if (pf) stageB(0, obuf, kn);
    __builtin_amdgcn_s_barrier();
    asm volatile("s_waitcnt lgkmcnt(0)" ::: "memory");
    MFMA_Q(0, 1)
    if (pf) asm volatile("s_waitcnt vmcnt(4)" ::: "memory");
    else    asm volatile("s_waitcnt vmcnt(0)" ::: "memory");
    __builtin_amdgcn_s_barrier();
    READ_A(1)
    if (pf) stageB(1, obuf, kn);
    __builtin_amdgcn_s_barrier();
    asm volatile("s_waitcnt lgkmcnt(0)" ::: "memory");
    MFMA_Q(1, 1)
    __builtin_amdgcn_s_barrier();
    READ_B(0)
    if (pf) stageA(1, obuf, kn);
    __builtin_amdgcn_s_barrier();
    asm volatile("s_waitcnt lgkmcnt(0)" ::: "memory");
    MFMA_Q(1, 0)
    if (pf) asm volatile("s_waitcnt vmcnt(4)" ::: "memory");
    __builtin_amdgcn_s_barrier();
  }
#undef READ_A
#undef READ_B
#undef MFMA_Q

  if (VSPLIT && bn >= 10) {
#pragma unroll
    for (int mh = 0; mh < 2; ++mh)
#pragma unroll
      for (int nh = 0; nh < 2; ++nh)
#pragma unroll
        for (int mfi = 0; mfi < 4; ++mfi)
#pragma unroll
          for (int nfi = 0; nfi < 2; ++nfi) {
            int row = bm * 256 + mh * 128 + mfi * 32 + wr * 16 + quad * 4;
            int cv  = bn * 256 + nh * 128 + nfi * 64 + wc * 16 + lrow - 2560;
            int b = row >> 11, tl = row & 2047;
            bf16x4 o;
#pragma unroll
            for (int r = 0; r < 4; ++r) o[r] = (bf16_t)acc[mh][nh][mfi][nfi][r];
            *(bf16x4*)&Vt[((size_t)(b * 512 + cv)) * 2048 + tl] = o;
          }
    return;
  }
#pragma unroll
  for (int mh = 0; mh < 2; ++mh)
#pragma unroll
    for (int nh = 0; nh < 2; ++nh)
#pragma unroll
      for (int mfi = 0; mfi < 4; ++mfi)
#pragma unroll
        for (int nfi = 0; nfi < 2; ++nfi)
#pragma unroll
          for (int r = 0; r < 4; ++r) {
            int row = bm * 256 + mh * 128 + mfi * 32 + wr * 16 + quad * 4 + r;
            int col = bn * 256 + nh * 128 + nfi * 64 + wc * 16 + lrow;
            if (F32OUT) ((float*)C)[(size_t)row * ldc + col] = acc[mh][nh][mfi][nfi][r];
            else        ((bf16_t*)C)[(size_t)row * ldc + col] = (bf16_t)acc[mh][nh][mfi][nfi][r];
          }
}

// ---------------- RoPE (in-place, layout (rows, nheads, 128), row stride param) ----------
__global__ void rope_kernel(bf16_t* __restrict__ X, const float* __restrict__ F,
                            int hshift, int stride) {
  int i = blockIdx.x * blockDim.x + threadIdx.x;
  int d = i & 63;
  int h = (i >> 6) & ((1 << hshift) - 1);
  int row = i >> (6 + hshift);
  int t = row & 2047;
  float c = F[t * 128 + d * 2];
  float s = F[t * 128 + d * 2 + 1];
  size_t base = (size_t)row * stride + h * 128 + d;
  float q0 = (float)X[base];
  float q1 = (float)X[base + 64];
  X[base]      = (bf16_t)(q0 * c - q1 * s);
  X[base + 64] = (bf16_t)(q1 * c + q0 * s);
}

// ---------------- Flash attention, causal, GQA 16q/4kv, D=128 ----------------
// K/V double-buffered in LDS; ONE __syncthreads per K-tile; T13 defer-max (thr=8, log2).
__global__ __launch_bounds__(256, 2) void attn_kernel(const bf16_t* __restrict__ QKV,
                                                      const float* __restrict__ F,
                                                      const bf16_t* __restrict__ Vt,
                                                      bf16_t* __restrict__ O) {
  __shared__ bf16_t Ks[2][64 * 128];   // [buf][key][d], chunk-swizzled
  __shared__ bf16_t Vs[2][128 * 64];   // [buf][d][key], chunk-swizzled
  __shared__ bf16_t Ps[4 * 32 * 64];   // per-wave, chunk-swizzled
  const int tid = threadIdx.x;
  const int wave = tid >> 6, lane = tid & 63;
  const int lrow = lane & 15, quad = lane >> 4;
  const int bh = blockIdx.y, b = bh >> 4, h = bh & 15, kvh = h >> 2;
  const size_t qoff  = ((size_t)b * 2048) * 2560 + (size_t)h * 128;
  const size_t koff  = ((size_t)b * 2048) * 2560 + 2048 + (size_t)kvh * 128;
  const size_t vtoff = ((size_t)(b * 4 + kvh) * 128) * 2048;
  const float qsc = 0.08838834764831845f * 1.44269504088896340736f;  // 1/sqrt(128)*log2(e)
  bf16_t* Pw = Ps + wave * (32 * 64);
  const float2* F2 = (const float2*)F;  // [t][64] (cos,sin)

  const int krow_l = tid >> 4;                   // 0..15
  const int kdc    = (tid & 15) ^ (krow_l & 7);  // K chunk swizzle
  const int vrow_l = tid >> 3;                   // 0..31
  const int vkc    = (tid & 7) ^ (vrow_l & 7);   // V chunk swizzle

  auto stage = [&](int kt, int bsel) {
    const bf16_t* Kg = QKV + koff + (size_t)(kt * 64) * 2560;
    const bf16_t* Vg = Vt + vtoff + kt * 64;
    bf16_t* Kd = &Ks[bsel][0];
    bf16_t* Vd = &Vs[bsel][0];
#pragma unroll
    for (int c4 = 0; c4 < 4; ++c4) {
      int ci = c4 * 256 + tid;
      async_load16(Kg + (size_t)(c4 * 16 + krow_l) * 2560 + kdc * 8, Kd + ci * 8);
      async_load16(Vg + (size_t)(c4 * 32 + vrow_l) * 2048 + vkc * 8, Vd + ci * 8);
    }
  };

  for (int phase = 0; phase < 2; ++phase) {
    const int qt = phase ? (15 - blockIdx.x) : blockIdx.x;
    const int qbase = qt * 128 + wave * 32;

    // Q B-frags with fused RoPE + scale: B[n=q][k=d]
    bf16x8 qf[2][4];
#pragma unroll
    for (int nt2 = 0; nt2 < 2; ++nt2) {
      const int t = qbase + nt2 * 16 + lrow;  // 0..2047
      const bf16_t* qp = QKV + qoff + (size_t)t * 2560 + quad * 8;
      bf16x8 raw[4];
#pragma unroll
      for (int ks = 0; ks < 4; ++ks) raw[ks] = *(const bf16x8*)(qp + ks * 32);
#pragma unroll
      for (int ks2 = 0; ks2 < 2; ++ks2) {
        bf16x8 lo, hi;
#pragma unroll
        for (int j = 0; j < 8; ++j) {
          int d = ks2 * 32 + quad * 8 + j;  // < 64
          float2 cs = F2[t * 64 + d];
          float q0 = (float)raw[ks2][j], q1 = (float)raw[ks2 + 2][j];
          lo[j] = (bf16_t)((q0 * cs.x - q1 * cs.y) * qsc);
          hi[j] = (bf16_t)((q1 * cs.x + q0 * cs.y) * qsc);
        }
        qf[nt2][ks2]     = lo;
        qf[nt2][ks2 + 2] = hi;
      }
    }

    f32x4 Oacc[2][8] = {};
    float m_r[2] = {-1.0e30f, -1.0e30f};
    float l_r[2] = {0.f, 0.f};
    const int kt_end = 2 * qt + 2;

    stage(0, 0);  // prime the pipeline

    for (int kt = 0; kt < kt_end; ++kt) {
      __syncthreads();
      if (kt + 1 < kt_end) stage(kt + 1, (kt + 1) & 1);
      const bf16_t* Kb_ = &Ks[kt & 1][0];
      const bf16_t* Vb_ = &Vs[kt & 1][0];

      if (kt * 64 <= qbase + 31) {  // wave-uniform skip of fully-masked tiles
        // S^T = K Q^T : C[m=key][n=q]
        f32x4 S[2][4] = {};
#pragma unroll
        for (int ks = 0; ks < 4; ++ks) {
          bf16x8 kf[4];
#pragma unroll
          for (int mt = 0; mt < 4; ++mt) {
            int dc = (ks * 4 + quad) ^ (lrow & 7);
            kf[mt] = *(const bf16x8*)&Kb_[(mt * 16 + lrow) * 128 + dc * 8];
          }
#pragma unroll
          for (int nt2 = 0; nt2 < 2; ++nt2)
#pragma unroll
            for (int mt = 0; mt < 4; ++mt)
              S[nt2][mt] = __builtin_amdgcn_mfma_f32_16x16x32_bf16(kf[mt], qf[nt2][ks], S[nt2][mt], 0, 0, 0);
        }
        // causal mask (diagonal tiles only). S^T: key=row, q=col.
        if (kt * 64 + 63 > qbase) {
#pragma unroll
          for (int nt2 = 0; nt2 < 2; ++nt2) {
            int q = qbase + nt2 * 16 + lrow;
#pragma unroll
            for (int mt = 0; mt < 4; ++mt) {
              int key0 = kt * 64 + mt * 16 + quad * 4;
#pragma unroll
              for (int r = 0; r < 4; ++r)
                if (key0 + r > q) S[nt2][mt][r] = -1.0e30f;
            }
          }
        }
        // online softmax (log2 domain); P -> Pw with chunk swizzle
        float alpha[2];
#pragma unroll
        for (int nt2 = 0; nt2 < 2; ++nt2) {
          float mx = -1.0e30f;
#pragma unroll
          for (int mt = 0; mt < 4; ++mt)
#pragma unroll
            for (int r = 0; r < 4; ++r) mx = fmaxf(mx, S[nt2][mt][r]);
          mx = fmaxf(mx, __shfl_xor(mx, 16, 64));
          mx = fmaxf(mx, __shfl_xor(mx, 32, 64));
          // T13 defer-max: only ratchet m when the tile max exceeds it by > 8
          float mold = m_r[nt2];
          float mnew = (mx - mold <= 8.0f) ? mold : mx;
          alpha[nt2] = fast_exp2(mold - mnew);  // exactly 1.0 when deferred
          m_r[nt2] = mnew;
          float rs = 0.f;
          const int prow = nt2 * 16 + lrow;
          const int pbase = prow * 64 + ((quad & 1) << 2);
#pragma unroll
          for (int mt = 0; mt < 4; ++mt) {
            bf16x4 pk;
#pragma unroll
            for (int r = 0; r < 4; ++r) {
              float p = fast_exp2(S[nt2][mt][r] - mnew);
              rs += p;
              pk[r] = (bf16_t)p;
            }
            int c8 = ((mt * 2 + (quad >> 1)) ^ (prow & 7)) << 3;
            *(bf16x4*)&Pw[pbase + c8] = pk;
          }
          rs += __shfl_xor(rs, 16, 64);
          rs += __shfl_xor(rs, 32, 64);
          l_r[nt2] = l_r[nt2] * alpha[nt2] + rs;
        }
        // lazy O rescale (rare after T13)
        bool nz = (alpha[0] != 1.f) || (alpha[1] != 1.f);
        if (__ballot(nz) != 0ull) {
#pragma unroll
          for (int mt2 = 0; mt2 < 2; ++mt2)
#pragma unroll
            for (int r = 0; r < 4; ++r) {
              float av = __shfl(alpha[mt2], quad * 4 + r, 16);
#pragma unroll
              for (int dt = 0; dt < 8; ++dt) Oacc[mt2][dt][r] *= av;
            }
        }
        // O += P V : A=P from Pw (swizzled), B=V^T from Vs (swizzled)
#pragma unroll
        for (int ks2 = 0; ks2 < 2; ++ks2) {
          bf16x8 ap[2];
#pragma unroll
          for (int mt2 = 0; mt2 < 2; ++mt2) {
            int prow = mt2 * 16 + lrow;
            ap[mt2] = *(const bf16x8*)&Pw[prow * 64 + (((ks2 * 4 + quad) ^ (prow & 7)) << 3)];
          }
          int dc = (ks2 * 4 + quad) ^ (lrow & 7);
#pragma unroll
          for (int dt = 0; dt < 8; ++dt) {
            bf16x8 bv = *(const bf16x8*)&Vb_[(dt * 16 + lrow) * 64 + dc * 8];
#pragma unroll
            for (int mt2 = 0; mt2 < 2; ++mt2)
              Oacc[mt2][dt] = __builtin_amdgcn_mfma_f32_16x16x32_bf16(ap[mt2], bv, Oacc[mt2][dt], 0, 0, 0);
          }
        }
      }
    }

    // epilogue: O /= l, store bf16 (Ab stride 2048)
#pragma unroll
    for (int mt2 = 0; mt2 < 2; ++mt2)
#pragma unroll
      for (int r = 0; r < 4; ++r) {
        float lv = __shfl(l_r[mt2], quad * 4 + r, 16);
        float inv = 1.0f / lv;
        int row = qbase + mt2 * 16 + quad * 4 + r;
#pragma unroll
        for (int dt = 0; dt < 8; ++dt)
          O[(size_t)b * 2048 * 2048 + (size_t)row * 2048 + h * 128 + dt * 16 + lrow] =
              (bf16_t)(Oacc[mt2][dt][r] * inv);
      }
  }
}

// ---------------- launch ----------------
extern "C" void kernel_launch(void* const* d_in, const int* in_sizes, int n_in,
                              void* d_out, int out_size, void* d_ws, size_t ws_size,
                              hipStream_t stream) {
  const float* x  = (const float*)d_in[0];
  const float* fc = (const float*)d_in[1];
  const float* Wq = (const float*)d_in[2];
  const float* Wk = (const float*)d_in[3];
  const float* Wv = (const float*)d_in[4];
  const float* Wo = (const float*)d_in[5];
  float* out = (float*)d_out;

  char* ws = (char*)d_ws;
  size_t off = 0;
  auto alloc = [&](size_t bytes) { char* p = ws + off; off += bytes; return p; };
  bf16_t* xb    = (bf16_t*)alloc((size_t)8192 * 2048 * 2);  // x bf16
  bf16_t* Wqkvb = (bf16_t*)alloc((size_t)3072 * 2048 * 2);  // [Wq; Wk; Wv] rows
  bf16_t* Wob   = (bf16_t*)alloc((size_t)2048 * 2048 * 2);
  bf16_t* QKVb  = (bf16_t*)alloc((size_t)8192 * 2560 * 2);  // [t][ Q(2048) | K(512) ]
  bf16_t* Ab    = (bf16_t*)alloc((size_t)8192 * 2048 * 2);
  bf16_t* Vtb   = (bf16_t*)alloc((size_t)2048 * 2048 * 2);  // V^T [(b*4+kvh)*128+d][t]
  (void)ws_size; (void)in_sizes; (void)n_in; (void)out_size;

  cvt_all<<<26624, 256, 0, stream>>>(x, Wq, Wk, Wv, Wo, xb, Wqkvb, Wob);

  // fused QKV projection: 256x128 tiles, 2-phase schedule -> 768 blocks = 3/CU balanced
  gemm_bal2<false, true><<<768, 512, 0, stream>>>(xb, Wqkvb, QKVb, Vtb, 24, 2048, 2560);

  // RoPE on K only (Q rope fused into attention); K cols 2048..2559, stride 2560
  rope_kernel<<<8192, 256, 0, stream>>>(QKVb + 2048, fc, 2, 2560);

  attn_kernel<<<dim3(8, 64), 256, 0, stream>>>(QKVb, fc, Vtb, Ab);

  // output projection (256^2 4-phase, 256 blocks = exactly 1/CU), f32 out
  gemm256<true, false><<<256, 512, 0, stream>>>(Ab, Wob, out, nullptr, 8, 2048, 2048);
}